// Round 12
// baseline (344.573 us; speedup 1.0000x reference)
//
#include <hip/hip_runtime.h>

// InvertedResidualQ on MI355X. Exact-integer quantized-conv formulation.
// R12: kconv2 reverted to R9 config (all tables in LDS, 4 blocks/CU — both
// diet directions measured slower). New: (a) guarded i16-d3 store path
// (exact integer; kout recomputes bn3 identically), (b) grid-level early-exit
// flags on the clipped max scans (benign race, result provably = 6.0).

#define HW    12544      // 112*112
#define WID   112
#define CIN   32
#define CMID  192
#define COUT  32
#define NB    32
#define NPIX  (NB*HW)        // 401408
#define NX    (NB*CIN*HW)    // 12845056

// workspace layout (bytes)
#define OFF_SCAL   0         // 4 u32: [0]=sx (plain store), 1..3 atomic-max s1,s2,s3
#define OFF_WSC    16        // 3 f32 weight scales
#define OFF_GF1    48        // global cap-flag for s1 scan
#define OFF_GF2    52        // global cap-flag for s2 scan
#define OFF_BN1    64        // gi[192], m[192], b[192]
#define OFF_BN2    2368
#define OFF_BN3    4672      // gi[32], m[32], b[32] (384B)
#define OFF_FQ1    5120      // A[192],B[192] f32, flag[192] u32, allfast u32
#define OFF_FQ2    7488
#define OFF_W1P    9856      // 192*8 u32 packed i8 conv1 weights (sdot4 path)
#define OFF_WDW    16000     // 192*9 f32 dw codes (kmax2)
#define OFF_W1A    22912     // 12*64*8B conv1 A-fragments
#define OFF_W2A    29056     // 2*6*64*8B conv2 A-fragments
#define OFF_WDWH   35200     // 48*9 uint2 (4x f16 dw codes per quad-tap)
#define OFF_PMAX   42112     // 2048 f32 per-block |x| partial maxes
#define OFF_XQ     65536     // NPIX*32 i8 packed input codes, [pix][ic]
#define OFF_D3     16777216  // optional: NPIX*32 i16 d3 (25690112 B)
#define D3_BYTES   25690112ULL

#define PADP(p) ((p) + ((p) >> 4))   // 16->17 row stride: kills LDS row aliasing

typedef int v4i __attribute__((ext_vector_type(4)));
typedef unsigned long long ull;
typedef _Float16 h2 __attribute__((ext_vector_type(2)));

__device__ __forceinline__ unsigned h2u(h2 v){ union{h2 h; unsigned u;} c; c.h=v; return c.u; }
__device__ __forceinline__ h2 u2h(unsigned u){ union{h2 h; unsigned u;} c; c.u=u; return c.h; }
__device__ __forceinline__ h2 pkrtz(float a, float b){
    auto r = __builtin_amdgcn_cvt_pkrtz(a, b);      // __fp16x2
    union { decltype(r) f; h2 h; } c; c.f = r; return c.h;
}

#if defined(__has_builtin)
#if __has_builtin(__builtin_amdgcn_sdot4)
#define HAVE_SDOT4 1
#endif
#endif

__device__ __forceinline__ int sdot4(unsigned a, unsigned b, int c) {
#ifdef HAVE_SDOT4
    return __builtin_amdgcn_sdot4((int)a, (int)b, c, false);
#else
    c += (int)(signed char)(a & 0xff)        * (int)(signed char)(b & 0xff);
    c += (int)(signed char)((a >> 8) & 0xff) * (int)(signed char)((b >> 8) & 0xff);
    c += (int)(signed char)((a >> 16) & 0xff)* (int)(signed char)((b >> 16) & 0xff);
    c += (int)(signed char)(a >> 24)         * (int)(signed char)(b >> 24);
    return c;
#endif
}

__device__ __forceinline__ v4i mfma_i8(ull a, ull b, v4i c) {
    return __builtin_amdgcn_mfma_i32_16x16x32_i8((long)a, (long)b, c, 0, 0, 0);
}

__device__ __forceinline__ float bmax256(float v, float* red) {
    const int t = threadIdx.x;
    red[t] = v; __syncthreads();
    for (int s = 128; s; s >>= 1) {
        if (t < s) red[t] = fmaxf(red[t], red[t + s]);
        __syncthreads();
    }
    float r = red[0]; __syncthreads();
    return r;
}

__device__ __forceinline__ float qcode(float x, float s, float n, float lo) {
    float t = x / s;
    t = fminf(fmaxf(t, lo), 1.0f);
    return rintf(__fmul_rn(t, n));
}

__device__ __forceinline__ float bnq(float d, float C, float m, float g, float b) {
    float y = __fmul_rn(d, C);
    float h = __fadd_rn(__fmul_rn(__fsub_rn(y, m), g), b);
    return fminf(fmaxf(h, 0.f), 6.f);
}

__device__ __forceinline__ float qexact15(float h, float s) {
    return rintf(__fmul_rn(fminf(h / s, 1.f), 15.f));
}
__device__ __forceinline__ float qfast15(float df, float A, float B) {
    float t = fmaf(df, A, B);
    return rintf(fminf(fmaxf(t, 0.f), 15.f));
}

// merged prep (block 0) + |x| partial max (all blocks -> pmax[block])
__global__ __launch_bounds__(256) void kprepx(
    const float4* __restrict__ x4,
    const float* __restrict__ w1, const float* __restrict__ wdw, const float* __restrict__ w2,
    const float* __restrict__ g1, const float* __restrict__ b1, const float* __restrict__ m1, const float* __restrict__ v1,
    const float* __restrict__ g2, const float* __restrict__ b2, const float* __restrict__ m2, const float* __restrict__ v2,
    const float* __restrict__ g3, const float* __restrict__ b3, const float* __restrict__ m3, const float* __restrict__ v3,
    unsigned char* __restrict__ ws)
{
    __shared__ float red[256];
    const int t = threadIdx.x;

    if (blockIdx.x == 0) {
        unsigned* scal = (unsigned*)(ws + OFF_SCAL);
        float* wsc  = (float*)(ws + OFF_WSC);
        float* bn1  = (float*)(ws + OFF_BN1);
        float* bn2  = (float*)(ws + OFF_BN2);
        float* bn3  = (float*)(ws + OFF_BN3);
        unsigned* w1p = (unsigned*)(ws + OFF_W1P);
        float*  wdwf  = (float*)(ws + OFF_WDW);

        if (t < 4) scal[t] = 0u;
        if (t == 0) {
            ((unsigned*)(ws+OFF_FQ1))[576] = 1u; ((unsigned*)(ws+OFF_FQ2))[576] = 1u;
            *(unsigned*)(ws+OFF_GF1) = 0u; *(unsigned*)(ws+OFF_GF2) = 0u;
        }

        float m;
        m = 0.f; for (int i = t; i < CMID*CIN; i += 256) m = fmaxf(m, fabsf(w1[i]));
        float sw1 = bmax256(m, red) + 1e-8f;
        m = 0.f; for (int i = t; i < CMID*9; i += 256) m = fmaxf(m, fabsf(wdw[i]));
        float swd = bmax256(m, red) + 1e-8f;
        m = 0.f; for (int i = t; i < COUT*CMID; i += 256) m = fmaxf(m, fabsf(w2[i]));
        float sw2 = bmax256(m, red) + 1e-8f;
        if (t == 0) { wsc[0] = sw1; wsc[1] = swd; wsc[2] = sw2; }

        for (int i = t; i < CMID*8; i += 256) {
            int oc = i >> 3, j = i & 7;
            unsigned wword = 0;
#pragma unroll
            for (int k = 0; k < 4; ++k) {
                int code = (int)qcode(w1[oc*CIN + 4*j + k], sw1, 7.f, -1.f);
                wword |= ((unsigned)code & 0xffu) << (8*k);
            }
            w1p[i] = wword;
        }
        for (int i = t; i < CMID*9; i += 256) wdwf[i] = qcode(wdw[i], swd, 7.f, -1.f);

        // conv1 A-fragments
        for (int i = t; i < 12*64; i += 256) {
            int octile = i >> 6, l = i & 63;
            int oc = octile*16 + (l & 15), icb = (l >> 4) * 8;
            unsigned lo = 0, hi = 0;
#pragma unroll
            for (int k = 0; k < 4; ++k) {
                lo |= ((unsigned)(int)qcode(w1[oc*CIN + icb + k],     sw1, 7.f, -1.f) & 0xffu) << (8*k);
                hi |= ((unsigned)(int)qcode(w1[oc*CIN + icb + 4 + k], sw1, 7.f, -1.f) & 0xffu) << (8*k);
            }
            ((unsigned*)(ws + OFF_W1A))[i*2]   = lo;
            ((unsigned*)(ws + OFF_W1A))[i*2+1] = hi;
        }
        // conv2 A-fragments
        for (int i = t; i < 2*6*64; i += 256) {
            int oct = i / 384, rem = i % 384, chunk = rem >> 6, l = rem & 63;
            int oc = oct*16 + (l & 15), cb = chunk*32 + (l >> 4) * 8;
            unsigned lo = 0, hi = 0;
#pragma unroll
            for (int k = 0; k < 4; ++k) {
                lo |= ((unsigned)(int)qcode(w2[oc*CMID + cb + k],     sw2, 7.f, -1.f) & 0xffu) << (8*k);
                hi |= ((unsigned)(int)qcode(w2[oc*CMID + cb + 4 + k], sw2, 7.f, -1.f) & 0xffu) << (8*k);
            }
            ((unsigned*)(ws + OFF_W2A))[i*2]   = lo;
            ((unsigned*)(ws + OFF_W2A))[i*2+1] = hi;
        }
        // dw weights as packed f16 quad pairs
        for (int i = t; i < 48*9; i += 256) {
            int qg = i / 9, tap = i % 9;
            float c0 = qcode(wdw[(qg*4+0)*9 + tap], swd, 7.f, -1.f);
            float c1 = qcode(wdw[(qg*4+1)*9 + tap], swd, 7.f, -1.f);
            float c2 = qcode(wdw[(qg*4+2)*9 + tap], swd, 7.f, -1.f);
            float c3 = qcode(wdw[(qg*4+3)*9 + tap], swd, 7.f, -1.f);
            ((uint2*)(ws + OFF_WDWH))[i] = make_uint2(h2u(pkrtz(c0, c1)), h2u(pkrtz(c2, c3)));
        }

        for (int c = t; c < CMID; c += 256) {
            float vv1 = v1[c] + 1e-5f;
            bn1[c] = __fmul_rn(g1[c], (float)(1.0 / sqrt((double)vv1)));
            bn1[192+c] = m1[c]; bn1[384+c] = b1[c];
            float vv2 = v2[c] + 1e-5f;
            bn2[c] = __fmul_rn(g2[c], (float)(1.0 / sqrt((double)vv2)));
            bn2[192+c] = m2[c]; bn2[384+c] = b2[c];
        }
        for (int c = t; c < COUT; c += 256) {
            float vv3 = v3[c] + 1e-5f;
            bn3[c] = __fmul_rn(g3[c], (float)(1.0 / sqrt((double)vv3)));
            bn3[32+c] = m3[c]; bn3[64+c] = b3[c];
        }
    }

    float m = 0.f;
    for (size_t i = (size_t)blockIdx.x*256 + t; i < NX/4; i += (size_t)gridDim.x*256) {
        float4 v = x4[i];
        m = fmaxf(m, fmaxf(fmaxf(fabsf(v.x), fabsf(v.y)), fmaxf(fabsf(v.z), fabsf(v.w))));
    }
    float r = bmax256(m, red);
    if (t == 0) ((float*)(ws + OFF_PMAX))[blockIdx.x] = r;
}

// quantize x -> xq packed codes; conv1 max-scan with wave-ANY + global-flag exit
__global__ __launch_bounds__(256) void kmax1q(const float* __restrict__ x,
                                              unsigned char* __restrict__ ws)
{
    __shared__ unsigned s_w1p[CMID*8];
    __shared__ float s_bn1[576];
    __shared__ float red[256];
    const int t = threadIdx.x;

    {
        const uint4* src = (const uint4*)(ws + OFF_W1P);
        uint4* dst = (uint4*)s_w1p;
        for (int i = t; i < CMID*8/4; i += 256) dst[i] = src[i];
        const float* b = (const float*)(ws + OFF_BN1);
        for (int i = t; i < 576; i += 256) s_bn1[i] = b[i];
    }

    const float* wsc = (const float*)(ws + OFF_WSC);
    unsigned char* xq = ws + OFF_XQ;
    volatile const unsigned* vgf1 = (volatile const unsigned*)(ws + OFF_GF1);

    float pm = 0.f;
    const float* pmax = (const float*)(ws + OFF_PMAX);
    for (int i = t; i < 2048; i += 256) pm = fmaxf(pm, pmax[i]);
    float sxr = bmax256(pm, red);
    if (blockIdx.x == 0 && t == 0) ((unsigned*)(ws + OFF_SCAL))[0] = __float_as_uint(sxr);
    const float sx = sxr + 1e-8f;
    const float C1 = (float)(((double)sx / 7.0) * ((double)wsc[0] / 7.0));

    const int p = blockIdx.x * 256 + t;
    const int n = p / HW, pi = p % HW;
    const float* xp = x + (size_t)n * CIN * HW + pi;

    float kx[CIN];
#pragma unroll
    for (int ic = 0; ic < CIN; ++ic) {
        float v = xp[(size_t)ic * HW] / sx;
        v = fminf(fmaxf(v, -1.f), 1.f);
        kx[ic] = rintf(__fmul_rn(v, 7.f));
    }

    unsigned wb[8];
#pragma unroll
    for (int j = 0; j < 8; ++j) {
        unsigned b0 = (unsigned)(int)kx[4*j]     & 0xffu;
        unsigned b1 = (unsigned)(int)kx[4*j + 1] & 0xffu;
        unsigned b2 = (unsigned)(int)kx[4*j + 2] & 0xffu;
        unsigned b3 = (unsigned)(int)kx[4*j + 3] & 0xffu;
        wb[j] = b0 | (b1 << 8) | (b2 << 16) | (b3 << 24);
    }
    uint4* q4 = (uint4*)(xq + (size_t)p * 32);
    q4[0] = make_uint4(wb[0], wb[1], wb[2], wb[3]);
    q4[1] = make_uint4(wb[4], wb[5], wb[6], wb[7]);

    __syncthreads();

    float mx = 0.f;
    for (int oc = 0; oc < CMID; ++oc) {
        int d = 0;
#pragma unroll
        for (int j = 0; j < 8; ++j) d = sdot4(wb[j], s_w1p[oc*8 + j], d);
        float h = bnq((float)d, C1, s_bn1[192+oc], s_bn1[oc], s_bn1[384+oc]);
        mx = fmaxf(mx, h);
        if (__any(mx >= 6.0f)) {           // cap hit: global max is exactly 6
            if ((t & 63) == 0) atomicOr((unsigned*)(ws + OFF_GF1), 1u);
            break;
        }
        if ((oc & 7) == 7) {               // remote cap: skip rest (exact, benign race)
            unsigned f = ((t & 63) == 0) ? *vgf1 : 0u;
            if (__shfl(f, 0, 64)) break;
        }
    }
    float r = bmax256(mx, red);
    if (t == 0) atomicMax((unsigned*)(ws + OFF_SCAL) + 1, __float_as_uint(r));
}

// per-channel fast-quant coefficients + EXHAUSTIVE verification
__global__ __launch_bounds__(64) void kcoef(unsigned char* __restrict__ ws, int stage)
{
    const unsigned* scal = (const unsigned*)(ws + OFF_SCAL);
    const float* wsc = (const float*)(ws + OFF_WSC);
    const int c = blockIdx.x, lane = threadIdx.x;
    const float* bn = (const float*)(ws + (stage == 1 ? OFF_BN1 : OFF_BN2));
    float* fq = (float*)(ws + (stage == 1 ? OFF_FQ1 : OFF_FQ2));

    float C, s; int R;
    if (stage == 1) {
        float sx = __uint_as_float(scal[0]) + 1e-8f;
        C = (float)(((double)sx / 7.0) * ((double)wsc[0] / 7.0));
        s = __uint_as_float(scal[1]) + 1e-8f;
        R = 1568;
    } else {
        float s1 = __uint_as_float(scal[1]) + 1e-8f;
        C = (float)(((double)s1 / 15.0) * ((double)wsc[1] / 7.0));
        s = __uint_as_float(scal[2]) + 1e-8f;
        R = 945;
    }
    const float gi = bn[c], mm = bn[192+c], bb = bn[384+c];
    const float A = (float)((double)C * (double)gi * 15.0 / (double)s);
    const float B = (float)(((double)bb - (double)mm * (double)gi) * 15.0 / (double)s);

    bool bad = false;
    for (int d = -R + lane; d <= R; d += 64) {
        float df = (float)d;
        float je = qexact15(bnq(df, C, mm, gi, bb), s);
        float jf = qfast15(df, A, B);
        if (je != jf) bad = true;
    }
    bool any = __any(bad);
    if (lane == 0) {
        unsigned flagv = any ? 0u : 1u;
        fq[c] = A; fq[192+c] = B;
        ((unsigned*)fq)[384+c] = flagv;
        atomicAnd(((unsigned*)fq) + 576, flagv);
    }
}

// tile 14x14; conv1(sdot4)+dw max(h2) scan; block-ANY + global-flag exit
__global__ __launch_bounds__(256) void kmax2(unsigned char* __restrict__ ws)
{
    __shared__ unsigned s_w1p[CMID*8];
    __shared__ float s_wdw[CMID*9];
    __shared__ float s_bn2[576];
    __shared__ unsigned s_fq1[576];
    __shared__ float jl[8][256];
    __shared__ float red[256];
    __shared__ unsigned s_flag;
    const int t = threadIdx.x;

    {
        const uint4* sp = (const uint4*)(ws + OFF_W1P);
        uint4* dp = (uint4*)s_w1p;
        for (int i = t; i < CMID*8/4; i += 256) dp[i] = sp[i];
        const float* wp = (const float*)(ws + OFF_WDW);
        for (int i = t; i < CMID*9; i += 256) s_wdw[i] = wp[i];
        const float* b2p = (const float*)(ws + OFF_BN2);
        for (int i = t; i < 576; i += 256) s_bn2[i] = b2p[i];
        const unsigned* fp = (const unsigned*)(ws + OFF_FQ1);
        for (int i = t; i < 576; i += 256) s_fq1[i] = fp[i];
        if (t == 0) s_flag = 0u;
    }

    const unsigned* scal = (const unsigned*)(ws + OFF_SCAL);
    const float* wsc = (const float*)(ws + OFF_WSC);
    const float* gbn1 = (const float*)(ws + OFF_BN1);
    const unsigned char* xq = ws + OFF_XQ;
    volatile const unsigned* vgf2 = (volatile const unsigned*)(ws + OFF_GF2);

    const float sx  = __uint_as_float(scal[0]) + 1e-8f;
    const float s1v = __uint_as_float(scal[1]) + 1e-8f;
    const float C1  = (float)(((double)sx  / 7.0)  * ((double)wsc[0] / 7.0));
    const float C2  = (float)(((double)s1v / 15.0) * ((double)wsc[1] / 7.0));

    const int tile = blockIdx.x, n = blockIdx.y;
    const int ty = t >> 4, tx = t & 15;
    const int hy = (tile >> 3) * 14 - 1 + ty;
    const int wx = (tile & 7)  * 14 - 1 + tx;
    const bool inb = (hy >= 0 && hy < WID && wx >= 0 && wx < WID);
    const bool act = (ty < 14) && (tx < 14);

    unsigned wb[8];
    if (inb) {
        const uint4* q4 = (const uint4*)(xq + ((size_t)n * HW + hy * WID + wx) * 32);
        uint4 a = q4[0], b4 = q4[1];
        wb[0]=a.x; wb[1]=a.y; wb[2]=a.z; wb[3]=a.w;
        wb[4]=b4.x; wb[5]=b4.y; wb[6]=b4.z; wb[7]=b4.w;
    } else {
#pragma unroll
        for (int j = 0; j < 8; ++j) wb[j] = 0u;
    }
    __syncthreads();

    float mx = 0.f;
    for (int ph = 0; ph < CMID/8; ++ph) {
#pragma unroll
        for (int k = 0; k < 8; ++k) {
            const int c = ph*8 + k;
            int d1 = 0;
#pragma unroll
            for (int j = 0; j < 8; ++j) d1 = sdot4(wb[j], s_w1p[c*8 + j], d1);
            float j1 = 0.f;
            if (inb) {
                float d1f = (float)d1;
                if (s_fq1[384+c]) {
                    j1 = qfast15(d1f, __uint_as_float(s_fq1[c]), __uint_as_float(s_fq1[192+c]));
                } else {
                    float h1 = bnq(d1f, C1, gbn1[192+c], gbn1[c], gbn1[384+c]);
                    j1 = qexact15(h1, s1v);
                }
            }
            jl[k][t] = j1;
        }
        __syncthreads();
        if (act) {
#pragma unroll
            for (int k = 0; k < 8; ++k) {
                const int c = ph*8 + k;
                const float* wd = s_wdw + c * 9;
                float d2 = 0.f;
#pragma unroll
                for (int dy = 0; dy < 3; ++dy)
#pragma unroll
                    for (int dx = 0; dx < 3; ++dx)
                        d2 = fmaf(jl[k][(ty+dy)*16 + tx+dx], wd[dy*3+dx], d2);
                float h2 = bnq(d2, C2, s_bn2[192+c], s_bn2[c], s_bn2[384+c]);
                mx = fmaxf(mx, h2);
            }
        }
        if (mx >= 6.0f) s_flag = 1u;               // local cap (benign race)
        if (t == 0 && *vgf2) s_flag = 1u;          // remote cap (benign stale)
        __syncthreads();
        if (s_flag) {
            if (t == 0) atomicOr((unsigned*)(ws + OFF_GF2), 1u);
            break;                                  // max settled at cap (=6)
        }
    }
    float r = bmax256(mx, red);
    if (t == 0) atomicMax((unsigned*)(ws + OFF_SCAL) + 2, __float_as_uint(r));
}

// full chain with MFMA (R9 config: all tables in LDS). Stores d3 i16 (exact)
// if use16, else h3 f32.
__global__ __launch_bounds__(256, 4) void kconv2(unsigned char* __restrict__ ws,
                                                 float* __restrict__ h3,
                                                 short* __restrict__ d3,
                                                 int use16)
{
    __shared__ ull   s_w1a[12*64];
    __shared__ ull   s_w2a[2*6*64];
    __shared__ uint2 s_wdwh[48*9];
    __shared__ float s_fqA1[192], s_fqB1[192], s_fqA2[192], s_fqB2[192];
    __shared__ float s_bn3[96];
    __shared__ uint2 jlh[4][272];
    __shared__ unsigned j2buf[256][9];
    __shared__ int s_af1, s_af2;
    const int t = threadIdx.x;

    {
        const uint4* a = (const uint4*)(ws + OFF_W1A);
        uint4* da = (uint4*)s_w1a;
        for (int i = t; i < 384; i += 256) da[i] = a[i];
        const uint4* b = (const uint4*)(ws + OFF_W2A);
        uint4* db = (uint4*)s_w2a;
        for (int i = t; i < 384; i += 256) db[i] = b[i];
        const uint4* c = (const uint4*)(ws + OFF_WDWH);
        uint4* dc = (uint4*)s_wdwh;
        for (int i = t; i < 216; i += 256) dc[i] = c[i];
        const float* f1 = (const float*)(ws + OFF_FQ1);
        const float* f2 = (const float*)(ws + OFF_FQ2);
        for (int i = t; i < 192; i += 256) {
            s_fqA1[i] = f1[i]; s_fqB1[i] = f1[192+i];
            s_fqA2[i] = f2[i]; s_fqB2[i] = f2[192+i];
        }
        const float* b3p = (const float*)(ws + OFF_BN3);
        if (t < 96) s_bn3[t] = b3p[t];
        if (t == 0) {
            s_af1 = (int)((const unsigned*)(ws + OFF_FQ1))[576];
            s_af2 = (int)((const unsigned*)(ws + OFF_FQ2))[576];
        }
    }

    const unsigned* scal = (const unsigned*)(ws + OFF_SCAL);
    const float* wsc = (const float*)(ws + OFF_WSC);
    const float* gbn1 = (const float*)(ws + OFF_BN1);   // fallback only
    const float* gbn2 = (const float*)(ws + OFF_BN2);   // fallback only
    const unsigned char* xq = ws + OFF_XQ;

    const float sx  = __uint_as_float(scal[0]) + 1e-8f;
    const float s1v = __uint_as_float(scal[1]) + 1e-8f;
    const float s2v = __uint_as_float(scal[2]) + 1e-8f;
    const float C1  = (float)(((double)sx  / 7.0)  * ((double)wsc[0] / 7.0));
    const float C2  = (float)(((double)s1v / 15.0) * ((double)wsc[1] / 7.0));
    const float C3  = (float)(((double)s2v / 15.0) * ((double)wsc[2] / 7.0));

    const int tile = blockIdx.x, n = blockIdx.y;
    const int y0 = (tile >> 3) * 14, x0 = (tile & 7) * 14;
    const int lane = t & 63, wid = t >> 6;
    const int ty = t >> 4, tx = t & 15;
    const bool act = (ty < 14) && (tx < 14);
    const int px = lane & 15, kq = lane >> 4;

    ull  xb[4];
    bool okb[4];
#pragma unroll
    for (int i = 0; i < 4; ++i) {
        int g = 4*wid + i;
        int bhy = y0 - 1 + g, bwx = x0 - 1 + px;
        bool ok = (bhy >= 0) && (bhy < WID) && (bwx >= 0) && (bwx < WID);
        okb[i] = ok;
        ull v = 0;
        if (ok) v = *(const ull*)(xq + (((size_t)n * HW + bhy * WID + bwx) * 32 + kq * 8));
        xb[i] = v;
    }
    __syncthreads();

    v4i acc2[2][4];
#pragma unroll
    for (int o = 0; o < 2; ++o)
#pragma unroll
        for (int i = 0; i < 4; ++i) { acc2[o][i][0]=0; acc2[o][i][1]=0; acc2[o][i][2]=0; acc2[o][i][3]=0; }

    for (int ph = 0; ph < 12; ++ph) {
        ull a1 = s_w1a[ph*64 + lane];
        const int oc0 = ph*16 + kq*4;
        float4 A14 = *(const float4*)&s_fqA1[oc0];
        float4 B14 = *(const float4*)&s_fqB1[oc0];
#pragma unroll
        for (int i = 0; i < 4; ++i) {
            v4i z = {0,0,0,0};
            v4i d = mfma_i8(a1, xb[i], z);
            float4 j1v;
            if (s_af1) {
                j1v.x = okb[i] ? qfast15((float)d[0], A14.x, B14.x) : 0.f;
                j1v.y = okb[i] ? qfast15((float)d[1], A14.y, B14.y) : 0.f;
                j1v.z = okb[i] ? qfast15((float)d[2], A14.z, B14.z) : 0.f;
                j1v.w = okb[i] ? qfast15((float)d[3], A14.w, B14.w) : 0.f;
            } else {
                float jj[4];
#pragma unroll
                for (int r = 0; r < 4; ++r) {
                    int oc = oc0 + r;
                    float h1 = bnq((float)d[r], C1, gbn1[192+oc], gbn1[oc], gbn1[384+oc]);
                    jj[r] = okb[i] ? qexact15(h1, s1v) : 0.f;
                }
                j1v.x = jj[0]; j1v.y = jj[1]; j1v.z = jj[2]; j1v.w = jj[3];
            }
            jlh[kq][PADP((4*wid + i)*16 + px)] =
                make_uint2(h2u(pkrtz(j1v.x, j1v.y)), h2u(pkrtz(j1v.z, j1v.w)));
        }
        __syncthreads();

        unsigned pw[4] = {0u, 0u, 0u, 0u};
        if (act) {
#pragma unroll
            for (int q = 0; q < 4; ++q) {
                h2 s01 = u2h(0u), s23 = u2h(0u);
                const int qg = ph*4 + q;
#pragma unroll
                for (int dy = 0; dy < 3; ++dy)
#pragma unroll
                    for (int dx = 0; dx < 3; ++dx) {
                        uint2 jv = jlh[q][PADP((ty+dy)*16 + (tx+dx))];
                        uint2 wv = s_wdwh[qg*9 + dy*3 + dx];
                        s01 += u2h(jv.x) * u2h(wv.x);
                        s23 += u2h(jv.y) * u2h(wv.y);
                    }
                float f0 = (float)s01[0], f1 = (float)s01[1];
                float f2 = (float)s23[0], f3 = (float)s23[1];
                const int oc2 = ph*16 + q*4;
                float j2a, j2b, j2c, j2d;
                if (s_af2) {
                    float4 A24 = *(const float4*)&s_fqA2[oc2];
                    float4 B24 = *(const float4*)&s_fqB2[oc2];
                    j2a = qfast15(f0, A24.x, B24.x);
                    j2b = qfast15(f1, A24.y, B24.y);
                    j2c = qfast15(f2, A24.z, B24.z);
                    j2d = qfast15(f3, A24.w, B24.w);
                } else {
                    j2a = qexact15(bnq(f0, C2, gbn2[192+oc2],   gbn2[oc2],   gbn2[384+oc2]),   s2v);
                    j2b = qexact15(bnq(f1, C2, gbn2[192+oc2+1], gbn2[oc2+1], gbn2[384+oc2+1]), s2v);
                    j2c = qexact15(bnq(f2, C2, gbn2[192+oc2+2], gbn2[oc2+2], gbn2[384+oc2+2]), s2v);
                    j2d = qexact15(bnq(f3, C2, gbn2[192+oc2+3], gbn2[oc2+3], gbn2[384+oc2+3]), s2v);
                }
                pw[q] = ((unsigned)(int)j2a) | ((unsigned)(int)j2b << 8) |
                        ((unsigned)(int)j2c << 16) | ((unsigned)(int)j2d << 24);
            }
        }
#pragma unroll
        for (int q = 0; q < 4; ++q) j2buf[t][(ph & 1) * 4 + q] = pw[q];
        __syncthreads();

        if (ph & 1) {
            const int chunk = ph >> 1;
#pragma unroll
            for (int oct = 0; oct < 2; ++oct) {
                ull a2 = s_w2a[(oct*6 + chunk)*64 + lane];
#pragma unroll
                for (int i = 0; i < 4; ++i) {
                    int row = (4*wid + i)*16 + px;
                    unsigned w0 = j2buf[row][kq*2], w1 = j2buf[row][kq*2 + 1];
                    ull b2 = (ull)w0 | ((ull)w1 << 32);
                    acc2[oct][i] = mfma_i8(a2, b2, acc2[oct][i]);
                }
            }
        }
    }

    // bn3 (for max) + store d3 i16 (exact) or h3 f32; max|h3|
    float mx = 0.f;
#pragma unroll
    for (int oct = 0; oct < 2; ++oct)
#pragma unroll
        for (int i = 0; i < 4; ++i) {
            int g = 4*wid + i;
            if (g < 14 && px < 14) {
                int gy = y0 + g, gx = x0 + px;
#pragma unroll
                for (int r = 0; r < 4; ++r) {
                    int oc = oct*16 + kq*4 + r;
                    int dv = acc2[oct][i][r];
                    float y = __fmul_rn((float)dv, C3);
                    float h = __fadd_rn(__fmul_rn(__fsub_rn(y, s_bn3[32+oc]), s_bn3[oc]), s_bn3[64+oc]);
                    size_t idx = ((size_t)n * COUT + oc) * HW + gy * WID + gx;
                    if (use16) d3[idx] = (short)dv;   // exact integer, |d3|<=20160
                    else       h3[idx] = h;
                    mx = fmaxf(mx, fabsf(h));
                }
            }
        }
    __syncthreads();
    float* red = (float*)&j2buf[0][0];
    float r = bmax256(mx, red);
    if (t == 0) atomicMax((unsigned*)(ws + OFF_SCAL) + 3, __float_as_uint(r));
}

// fallback: out = x + actq_signed(h3) with h3 f32 staged in d_out
__global__ __launch_bounds__(256) void kout(const float4* __restrict__ x4,
                                            float4* __restrict__ io4,
                                            const unsigned char* __restrict__ ws)
{
    const unsigned* scal = (const unsigned*)(ws + OFF_SCAL);
    const float s3v = __uint_as_float(scal[3]) + 1e-8f;

    for (size_t i = (size_t)blockIdx.x*256 + threadIdx.x; i < NX/4; i += (size_t)gridDim.x*256) {
        float4 h = io4[i], xv = x4[i], o;
        float* hp = &h.x; float* xp = &xv.x; float* op = &o.x;
#pragma unroll
        for (int k = 0; k < 4; ++k) {
            float tq = fminf(fmaxf(hp[k] / s3v, -1.f), 1.f);
            float kq = rintf(__fmul_rn(tq, 7.f));
            float q  = __fmul_rn(kq / 7.f, s3v);
            op[k] = __fadd_rn(xp[k], q);
        }
        io4[i] = o;
    }
}

// i16 path: recompute h = bn3(d3) with the IDENTICAL chain (bit-exact), then
// out = x + actq_signed(h). d3 layout matches h3: [n][oc][pix].
__global__ __launch_bounds__(256) void kout16(const float4* __restrict__ x4,
                                              float4* __restrict__ out4,
                                              const short* __restrict__ d3,
                                              const unsigned char* __restrict__ ws)
{
    const unsigned* scal = (const unsigned*)(ws + OFF_SCAL);
    const float* wsc = (const float*)(ws + OFF_WSC);
    const float* bn3 = (const float*)(ws + OFF_BN3);
    const float s2v = __uint_as_float(scal[2]) + 1e-8f;
    const float s3v = __uint_as_float(scal[3]) + 1e-8f;
    const float C3  = (float)(((double)s2v / 15.0) * ((double)wsc[2] / 7.0));

    for (size_t i = (size_t)blockIdx.x*256 + threadIdx.x; i < NX/4; i += (size_t)gridDim.x*256) {
        const int oc = (int)((i * 4) / HW) & 31;      // row = n*32+oc; same oc for all 4
        const float g = bn3[oc], m = bn3[32+oc], b = bn3[64+oc];
        uint2 dv = ((const uint2*)d3)[i];
        int s0 = (int)(short)(dv.x & 0xffffu), s1 = (int)(short)(dv.x >> 16);
        int s2 = (int)(short)(dv.y & 0xffffu), s3 = (int)(short)(dv.y >> 16);
        int sv[4] = {s0, s1, s2, s3};
        float4 xv = x4[i], o;
        float* xp = &xv.x; float* op = &o.x;
#pragma unroll
        for (int k = 0; k < 4; ++k) {
            float y = __fmul_rn((float)sv[k], C3);
            float h = __fadd_rn(__fmul_rn(__fsub_rn(y, m), g), b);   // == kconv2's h
            float tq = fminf(fmaxf(h / s3v, -1.f), 1.f);
            float kq = rintf(__fmul_rn(tq, 7.f));
            float q  = __fmul_rn(kq / 7.f, s3v);
            op[k] = __fadd_rn(xp[k], q);
        }
        out4[i] = o;
    }
}

extern "C" void kernel_launch(void* const* d_in, const int* in_sizes, int n_in,
                              void* d_out, int out_size, void* d_ws, size_t ws_size,
                              hipStream_t stream)
{
    const float* x   = (const float*)d_in[0];
    const float* w1  = (const float*)d_in[1];
    const float* g1  = (const float*)d_in[2];
    const float* b1  = (const float*)d_in[3];
    const float* m1  = (const float*)d_in[4];
    const float* v1  = (const float*)d_in[5];
    const float* wdw = (const float*)d_in[6];
    const float* g2  = (const float*)d_in[7];
    const float* b2  = (const float*)d_in[8];
    const float* m2  = (const float*)d_in[9];
    const float* v2  = (const float*)d_in[10];
    const float* w2  = (const float*)d_in[11];
    const float* g3  = (const float*)d_in[12];
    const float* b3  = (const float*)d_in[13];
    const float* m3  = (const float*)d_in[14];
    const float* v3  = (const float*)d_in[15];
    unsigned char* ws = (unsigned char*)d_ws;

    const int use16 = (ws_size >= (size_t)OFF_D3 + D3_BYTES) ? 1 : 0;
    short* d3 = (short*)(ws + OFF_D3);

    hipLaunchKernelGGL(kprepx, dim3(2048), dim3(256), 0, stream, (const float4*)x,
                       w1, wdw, w2, g1, b1, m1, v1, g2, b2, m2, v2, g3, b3, m3, v3, ws);
    hipLaunchKernelGGL(kmax1q, dim3(NPIX/256), dim3(256), 0, stream, x, ws);
    hipLaunchKernelGGL(kcoef, dim3(CMID), dim3(64), 0, stream, ws, 1);
    hipLaunchKernelGGL(kmax2, dim3(64, NB), dim3(256), 0, stream, ws);
    hipLaunchKernelGGL(kcoef, dim3(CMID), dim3(64), 0, stream, ws, 2);
    hipLaunchKernelGGL(kconv2, dim3(64, NB), dim3(256), 0, stream, ws,
                       (float*)d_out, d3, use16);
    if (use16) {
        hipLaunchKernelGGL(kout16, dim3(2048), dim3(256), 0, stream,
                           (const float4*)x, (float4*)d_out, (const short*)d3, ws);
    } else {
        hipLaunchKernelGGL(kout, dim3(2048), dim3(256), 0, stream,
                           (const float4*)x, (float4*)d_out, ws);
    }
}

// Round 14
// 228.833 us; speedup vs baseline: 1.5058x; 1.5058x over previous
//
#include <hip/hip_runtime.h>

// InvertedResidualQ on MI355X. Exact-integer quantized-conv formulation.
// R14 = R9 verbatim (the reliably-passing optimum: 229us, 3 passes).
// R13's i16-d3 staging dropped: it caused an intermittent post-timing
// divergence (replay-dependent). kconv2: all tables in LDS, 4 blocks/CU.

#define HW    12544      // 112*112
#define WID   112
#define CIN   32
#define CMID  192
#define COUT  32
#define NB    32
#define NPIX  (NB*HW)        // 401408
#define NX    (NB*CIN*HW)    // 12845056

// workspace layout (bytes)
#define OFF_SCAL   0         // 4 u32: [0]=sx (plain store), 1..3 atomic-max s1,s2,s3
#define OFF_WSC    16        // 3 f32 weight scales
#define OFF_BN1    64        // gi[192], m[192], b[192]
#define OFF_BN2    2368
#define OFF_BN3    4672      // gi[32], m[32], b[32] (384B)
#define OFF_FQ1    5120      // A[192],B[192] f32, flag[192] u32, allfast u32
#define OFF_FQ2    7488
#define OFF_W1P    9856      // 192*8 u32 packed i8 conv1 weights (sdot4 path)
#define OFF_WDW    16000     // 192*9 f32 dw codes (kmax2)
#define OFF_W1A    22912     // 12*64*8B conv1 A-fragments
#define OFF_W2A    29056     // 2*6*64*8B conv2 A-fragments
#define OFF_WDWH   35200     // 48*9 uint2 (4x f16 dw codes per quad-tap)
#define OFF_PMAX   42112     // 2048 f32 per-block |x| partial maxes
#define OFF_XQ     65536     // NPIX*32 i8 packed input codes, [pix][ic]

#define PADP(p) ((p) + ((p) >> 4))   // 16->17 row stride: kills LDS row aliasing

typedef int v4i __attribute__((ext_vector_type(4)));
typedef unsigned long long ull;
typedef _Float16 h2 __attribute__((ext_vector_type(2)));

__device__ __forceinline__ unsigned h2u(h2 v){ union{h2 h; unsigned u;} c; c.h=v; return c.u; }
__device__ __forceinline__ h2 u2h(unsigned u){ union{h2 h; unsigned u;} c; c.u=u; return c.h; }
__device__ __forceinline__ h2 pkrtz(float a, float b){
    auto r = __builtin_amdgcn_cvt_pkrtz(a, b);      // __fp16x2
    union { decltype(r) f; h2 h; } c; c.f = r; return c.h;
}

#if defined(__has_builtin)
#if __has_builtin(__builtin_amdgcn_sdot4)
#define HAVE_SDOT4 1
#endif
#endif

__device__ __forceinline__ int sdot4(unsigned a, unsigned b, int c) {
#ifdef HAVE_SDOT4
    return __builtin_amdgcn_sdot4((int)a, (int)b, c, false);
#else
    c += (int)(signed char)(a & 0xff)        * (int)(signed char)(b & 0xff);
    c += (int)(signed char)((a >> 8) & 0xff) * (int)(signed char)((b >> 8) & 0xff);
    c += (int)(signed char)((a >> 16) & 0xff)* (int)(signed char)((b >> 16) & 0xff);
    c += (int)(signed char)(a >> 24)         * (int)(signed char)(b >> 24);
    return c;
#endif
}

__device__ __forceinline__ v4i mfma_i8(ull a, ull b, v4i c) {
    return __builtin_amdgcn_mfma_i32_16x16x32_i8((long)a, (long)b, c, 0, 0, 0);
}

__device__ __forceinline__ float bmax256(float v, float* red) {
    const int t = threadIdx.x;
    red[t] = v; __syncthreads();
    for (int s = 128; s; s >>= 1) {
        if (t < s) red[t] = fmaxf(red[t], red[t + s]);
        __syncthreads();
    }
    float r = red[0]; __syncthreads();
    return r;
}

__device__ __forceinline__ float qcode(float x, float s, float n, float lo) {
    float t = x / s;
    t = fminf(fmaxf(t, lo), 1.0f);
    return rintf(__fmul_rn(t, n));
}

__device__ __forceinline__ float bnq(float d, float C, float m, float g, float b) {
    float y = __fmul_rn(d, C);
    float h = __fadd_rn(__fmul_rn(__fsub_rn(y, m), g), b);
    return fminf(fmaxf(h, 0.f), 6.f);
}

__device__ __forceinline__ float qexact15(float h, float s) {
    return rintf(__fmul_rn(fminf(h / s, 1.f), 15.f));
}
__device__ __forceinline__ float qfast15(float df, float A, float B) {
    float t = fmaf(df, A, B);
    return rintf(fminf(fmaxf(t, 0.f), 15.f));
}

// merged prep (block 0) + |x| partial max (all blocks -> pmax[block])
__global__ __launch_bounds__(256) void kprepx(
    const float4* __restrict__ x4,
    const float* __restrict__ w1, const float* __restrict__ wdw, const float* __restrict__ w2,
    const float* __restrict__ g1, const float* __restrict__ b1, const float* __restrict__ m1, const float* __restrict__ v1,
    const float* __restrict__ g2, const float* __restrict__ b2, const float* __restrict__ m2, const float* __restrict__ v2,
    const float* __restrict__ g3, const float* __restrict__ b3, const float* __restrict__ m3, const float* __restrict__ v3,
    unsigned char* __restrict__ ws)
{
    __shared__ float red[256];
    const int t = threadIdx.x;

    if (blockIdx.x == 0) {
        unsigned* scal = (unsigned*)(ws + OFF_SCAL);
        float* wsc  = (float*)(ws + OFF_WSC);
        float* bn1  = (float*)(ws + OFF_BN1);
        float* bn2  = (float*)(ws + OFF_BN2);
        float* bn3  = (float*)(ws + OFF_BN3);
        unsigned* w1p = (unsigned*)(ws + OFF_W1P);
        float*  wdwf  = (float*)(ws + OFF_WDW);

        if (t < 4) scal[t] = 0u;
        if (t == 0) { ((unsigned*)(ws+OFF_FQ1))[576] = 1u; ((unsigned*)(ws+OFF_FQ2))[576] = 1u; }

        float m;
        m = 0.f; for (int i = t; i < CMID*CIN; i += 256) m = fmaxf(m, fabsf(w1[i]));
        float sw1 = bmax256(m, red) + 1e-8f;
        m = 0.f; for (int i = t; i < CMID*9; i += 256) m = fmaxf(m, fabsf(wdw[i]));
        float swd = bmax256(m, red) + 1e-8f;
        m = 0.f; for (int i = t; i < COUT*CMID; i += 256) m = fmaxf(m, fabsf(w2[i]));
        float sw2 = bmax256(m, red) + 1e-8f;
        if (t == 0) { wsc[0] = sw1; wsc[1] = swd; wsc[2] = sw2; }

        // packed i8 conv1 weights (sdot4 path, kmax1q/kmax2)
        for (int i = t; i < CMID*8; i += 256) {
            int oc = i >> 3, j = i & 7;
            unsigned wword = 0;
#pragma unroll
            for (int k = 0; k < 4; ++k) {
                int code = (int)qcode(w1[oc*CIN + 4*j + k], sw1, 7.f, -1.f);
                wword |= ((unsigned)code & 0xffu) << (8*k);
            }
            w1p[i] = wword;
        }
        for (int i = t; i < CMID*9; i += 256) wdwf[i] = qcode(wdw[i], swd, 7.f, -1.f);

        // conv1 A-fragments: [octile][lane] 8B, oc = octile*16+(l&15), ic = (l>>4)*8+e
        for (int i = t; i < 12*64; i += 256) {
            int octile = i >> 6, l = i & 63;
            int oc = octile*16 + (l & 15), icb = (l >> 4) * 8;
            unsigned lo = 0, hi = 0;
#pragma unroll
            for (int k = 0; k < 4; ++k) {
                lo |= ((unsigned)(int)qcode(w1[oc*CIN + icb + k],     sw1, 7.f, -1.f) & 0xffu) << (8*k);
                hi |= ((unsigned)(int)qcode(w1[oc*CIN + icb + 4 + k], sw1, 7.f, -1.f) & 0xffu) << (8*k);
            }
            ((unsigned*)(ws + OFF_W1A))[i*2]   = lo;
            ((unsigned*)(ws + OFF_W1A))[i*2+1] = hi;
        }
        // conv2 A-fragments: [oct][chunk][lane] 8B, oc = oct*16+(l&15), ch = chunk*32+(l>>4)*8+e
        for (int i = t; i < 2*6*64; i += 256) {
            int oct = i / 384, rem = i % 384, chunk = rem >> 6, l = rem & 63;
            int oc = oct*16 + (l & 15), cb = chunk*32 + (l >> 4) * 8;
            unsigned lo = 0, hi = 0;
#pragma unroll
            for (int k = 0; k < 4; ++k) {
                lo |= ((unsigned)(int)qcode(w2[oc*CMID + cb + k],     sw2, 7.f, -1.f) & 0xffu) << (8*k);
                hi |= ((unsigned)(int)qcode(w2[oc*CMID + cb + 4 + k], sw2, 7.f, -1.f) & 0xffu) << (8*k);
            }
            ((unsigned*)(ws + OFF_W2A))[i*2]   = lo;
            ((unsigned*)(ws + OFF_W2A))[i*2+1] = hi;
        }
        // dw weights as packed f16 quad pairs: [qg][tap] -> 2x half2 (exact ints)
        for (int i = t; i < 48*9; i += 256) {
            int qg = i / 9, tap = i % 9;
            float c0 = qcode(wdw[(qg*4+0)*9 + tap], swd, 7.f, -1.f);
            float c1 = qcode(wdw[(qg*4+1)*9 + tap], swd, 7.f, -1.f);
            float c2 = qcode(wdw[(qg*4+2)*9 + tap], swd, 7.f, -1.f);
            float c3 = qcode(wdw[(qg*4+3)*9 + tap], swd, 7.f, -1.f);
            ((uint2*)(ws + OFF_WDWH))[i] = make_uint2(h2u(pkrtz(c0, c1)), h2u(pkrtz(c2, c3)));
        }

        for (int c = t; c < CMID; c += 256) {
            float vv1 = v1[c] + 1e-5f;
            bn1[c] = __fmul_rn(g1[c], (float)(1.0 / sqrt((double)vv1)));
            bn1[192+c] = m1[c]; bn1[384+c] = b1[c];
            float vv2 = v2[c] + 1e-5f;
            bn2[c] = __fmul_rn(g2[c], (float)(1.0 / sqrt((double)vv2)));
            bn2[192+c] = m2[c]; bn2[384+c] = b2[c];
        }
        for (int c = t; c < COUT; c += 256) {
            float vv3 = v3[c] + 1e-5f;
            bn3[c] = __fmul_rn(g3[c], (float)(1.0 / sqrt((double)vv3)));
            bn3[32+c] = m3[c]; bn3[64+c] = b3[c];
        }
    }

    // |x| partial max -> pmax[blockIdx.x] (plain store, no reset race)
    float m = 0.f;
    for (size_t i = (size_t)blockIdx.x*256 + t; i < NX/4; i += (size_t)gridDim.x*256) {
        float4 v = x4[i];
        m = fmaxf(m, fmaxf(fmaxf(fabsf(v.x), fabsf(v.y)), fmaxf(fabsf(v.z), fabsf(v.w))));
    }
    float r = bmax256(m, red);
    if (t == 0) ((float*)(ws + OFF_PMAX))[blockIdx.x] = r;
}

// quantize x -> xq packed codes; conv1 max-scan (sdot4) with wave ANY-exit
__global__ __launch_bounds__(256) void kmax1q(const float* __restrict__ x,
                                              unsigned char* __restrict__ ws)
{
    __shared__ unsigned s_w1p[CMID*8];
    __shared__ float s_bn1[576];
    __shared__ float red[256];
    const int t = threadIdx.x;

    {
        const uint4* src = (const uint4*)(ws + OFF_W1P);
        uint4* dst = (uint4*)s_w1p;
        for (int i = t; i < CMID*8/4; i += 256) dst[i] = src[i];
        const float* b = (const float*)(ws + OFF_BN1);
        for (int i = t; i < 576; i += 256) s_bn1[i] = b[i];
    }

    const float* wsc = (const float*)(ws + OFF_WSC);
    unsigned char* xq = ws + OFF_XQ;

    // self-reduce per-block partials -> sx (identical in every block)
    float pm = 0.f;
    const float* pmax = (const float*)(ws + OFF_PMAX);
    for (int i = t; i < 2048; i += 256) pm = fmaxf(pm, pmax[i]);
    float sxr = bmax256(pm, red);
    if (blockIdx.x == 0 && t == 0) ((unsigned*)(ws + OFF_SCAL))[0] = __float_as_uint(sxr);
    const float sx = sxr + 1e-8f;
    const float C1 = (float)(((double)sx / 7.0) * ((double)wsc[0] / 7.0));

    const int p = blockIdx.x * 256 + t;
    const int n = p / HW, pi = p % HW;
    const float* xp = x + (size_t)n * CIN * HW + pi;

    float kx[CIN];
#pragma unroll
    for (int ic = 0; ic < CIN; ++ic) {
        float v = xp[(size_t)ic * HW] / sx;
        v = fminf(fmaxf(v, -1.f), 1.f);
        kx[ic] = rintf(__fmul_rn(v, 7.f));
    }

    unsigned wb[8];
#pragma unroll
    for (int j = 0; j < 8; ++j) {
        unsigned b0 = (unsigned)(int)kx[4*j]     & 0xffu;
        unsigned b1 = (unsigned)(int)kx[4*j + 1] & 0xffu;
        unsigned b2 = (unsigned)(int)kx[4*j + 2] & 0xffu;
        unsigned b3 = (unsigned)(int)kx[4*j + 3] & 0xffu;
        wb[j] = b0 | (b1 << 8) | (b2 << 16) | (b3 << 24);
    }
    uint4* q4 = (uint4*)(xq + (size_t)p * 32);
    q4[0] = make_uint4(wb[0], wb[1], wb[2], wb[3]);
    q4[1] = make_uint4(wb[4], wb[5], wb[6], wb[7]);

    __syncthreads();

    float mx = 0.f;
    for (int oc = 0; oc < CMID; ++oc) {
        int d = 0;
#pragma unroll
        for (int j = 0; j < 8; ++j) d = sdot4(wb[j], s_w1p[oc*8 + j], d);
        float h = bnq((float)d, C1, s_bn1[192+oc], s_bn1[oc], s_bn1[384+oc]);
        mx = fmaxf(mx, h);
        if (__any(mx >= 6.0f)) break;    // any lane capped -> wave max settled (=6)
    }
    float r = bmax256(mx, red);
    if (t == 0) atomicMax((unsigned*)(ws + OFF_SCAL) + 1, __float_as_uint(r));
}

// per-channel fast-quant coefficients + EXHAUSTIVE verification
__global__ __launch_bounds__(64) void kcoef(unsigned char* __restrict__ ws, int stage)
{
    const unsigned* scal = (const unsigned*)(ws + OFF_SCAL);
    const float* wsc = (const float*)(ws + OFF_WSC);
    const int c = blockIdx.x, lane = threadIdx.x;
    const float* bn = (const float*)(ws + (stage == 1 ? OFF_BN1 : OFF_BN2));
    float* fq = (float*)(ws + (stage == 1 ? OFF_FQ1 : OFF_FQ2));

    float C, s; int R;
    if (stage == 1) {
        float sx = __uint_as_float(scal[0]) + 1e-8f;
        C = (float)(((double)sx / 7.0) * ((double)wsc[0] / 7.0));
        s = __uint_as_float(scal[1]) + 1e-8f;
        R = 1568;
    } else {
        float s1 = __uint_as_float(scal[1]) + 1e-8f;
        C = (float)(((double)s1 / 15.0) * ((double)wsc[1] / 7.0));
        s = __uint_as_float(scal[2]) + 1e-8f;
        R = 945;
    }
    const float gi = bn[c], mm = bn[192+c], bb = bn[384+c];
    const float A = (float)((double)C * (double)gi * 15.0 / (double)s);
    const float B = (float)(((double)bb - (double)mm * (double)gi) * 15.0 / (double)s);

    bool bad = false;
    for (int d = -R + lane; d <= R; d += 64) {
        float df = (float)d;
        float je = qexact15(bnq(df, C, mm, gi, bb), s);
        float jf = qfast15(df, A, B);
        if (je != jf) bad = true;
    }
    bool any = __any(bad);
    if (lane == 0) {
        unsigned flagv = any ? 0u : 1u;
        fq[c] = A; fq[192+c] = B;
        ((unsigned*)fq)[384+c] = flagv;
        atomicAnd(((unsigned*)fq) + 576, flagv);
    }
}

// tile 14x14 out, halo 16x16 = 256 = blockDim; conv1(sdot4)+dw max(h2) scan
// with block-local ANY-hit early exit (cap 6). (usually exits after 1 phase)
__global__ __launch_bounds__(256) void kmax2(unsigned char* __restrict__ ws)
{
    __shared__ unsigned s_w1p[CMID*8];
    __shared__ float s_wdw[CMID*9];
    __shared__ float s_bn2[576];
    __shared__ unsigned s_fq1[576];
    __shared__ float jl[8][256];
    __shared__ float red[256];
    __shared__ unsigned s_flag;
    const int t = threadIdx.x;

    {
        const uint4* sp = (const uint4*)(ws + OFF_W1P);
        uint4* dp = (uint4*)s_w1p;
        for (int i = t; i < CMID*8/4; i += 256) dp[i] = sp[i];
        const float* wp = (const float*)(ws + OFF_WDW);
        for (int i = t; i < CMID*9; i += 256) s_wdw[i] = wp[i];
        const float* b2p = (const float*)(ws + OFF_BN2);
        for (int i = t; i < 576; i += 256) s_bn2[i] = b2p[i];
        const unsigned* fp = (const unsigned*)(ws + OFF_FQ1);
        for (int i = t; i < 576; i += 256) s_fq1[i] = fp[i];
        if (t == 0) s_flag = 0u;
    }

    const unsigned* scal = (const unsigned*)(ws + OFF_SCAL);
    const float* wsc = (const float*)(ws + OFF_WSC);
    const float* gbn1 = (const float*)(ws + OFF_BN1);
    const unsigned char* xq = ws + OFF_XQ;

    const float sx  = __uint_as_float(scal[0]) + 1e-8f;
    const float s1v = __uint_as_float(scal[1]) + 1e-8f;
    const float C1  = (float)(((double)sx  / 7.0)  * ((double)wsc[0] / 7.0));
    const float C2  = (float)(((double)s1v / 15.0) * ((double)wsc[1] / 7.0));

    const int tile = blockIdx.x, n = blockIdx.y;
    const int ty = t >> 4, tx = t & 15;
    const int hy = (tile >> 3) * 14 - 1 + ty;
    const int wx = (tile & 7)  * 14 - 1 + tx;
    const bool inb = (hy >= 0 && hy < WID && wx >= 0 && wx < WID);
    const bool act = (ty < 14) && (tx < 14);

    unsigned wb[8];
    if (inb) {
        const uint4* q4 = (const uint4*)(xq + ((size_t)n * HW + hy * WID + wx) * 32);
        uint4 a = q4[0], b4 = q4[1];
        wb[0]=a.x; wb[1]=a.y; wb[2]=a.z; wb[3]=a.w;
        wb[4]=b4.x; wb[5]=b4.y; wb[6]=b4.z; wb[7]=b4.w;
    } else {
#pragma unroll
        for (int j = 0; j < 8; ++j) wb[j] = 0u;
    }
    __syncthreads();

    float mx = 0.f;
    for (int ph = 0; ph < CMID/8; ++ph) {
#pragma unroll
        for (int k = 0; k < 8; ++k) {
            const int c = ph*8 + k;
            int d1 = 0;
#pragma unroll
            for (int j = 0; j < 8; ++j) d1 = sdot4(wb[j], s_w1p[c*8 + j], d1);
            float j1 = 0.f;
            if (inb) {
                float d1f = (float)d1;
                if (s_fq1[384+c]) {
                    j1 = qfast15(d1f, __uint_as_float(s_fq1[c]), __uint_as_float(s_fq1[192+c]));
                } else {
                    float h1 = bnq(d1f, C1, gbn1[192+c], gbn1[c], gbn1[384+c]);
                    j1 = qexact15(h1, s1v);
                }
            }
            jl[k][t] = j1;
        }
        __syncthreads();
        if (act) {
#pragma unroll
            for (int k = 0; k < 8; ++k) {
                const int c = ph*8 + k;
                const float* wd = s_wdw + c * 9;
                float d2 = 0.f;
#pragma unroll
                for (int dy = 0; dy < 3; ++dy)
#pragma unroll
                    for (int dx = 0; dx < 3; ++dx)
                        d2 = fmaf(jl[k][(ty+dy)*16 + tx+dx], wd[dy*3+dx], d2);
                float h2 = bnq(d2, C2, s_bn2[192+c], s_bn2[c], s_bn2[384+c]);
                mx = fmaxf(mx, h2);
            }
        }
        if (mx >= 6.0f) s_flag = 1u;    // benign race; visible after barrier
        __syncthreads();
        if (s_flag) break;              // block max settled at cap (=6)
    }
    float r = bmax256(mx, red);
    if (t == 0) atomicMax((unsigned*)(ws + OFF_SCAL) + 2, __float_as_uint(r));
}

// full chain with MFMA: conv1 MFMA -> j1 (f16 quads, padded LDS) -> dw (pk f16)
// -> j2 bytes (9-word rows) -> conv2 MFMA. All tables in LDS (R9 config).
__global__ __launch_bounds__(256, 4) void kconv2(unsigned char* __restrict__ ws,
                                                 float* __restrict__ h3)
{
    __shared__ ull   s_w1a[12*64];
    __shared__ ull   s_w2a[2*6*64];
    __shared__ uint2 s_wdwh[48*9];
    __shared__ float s_fqA1[192], s_fqB1[192], s_fqA2[192], s_fqB2[192];
    __shared__ float s_bn3[96];
    __shared__ uint2 jlh[4][272];           // [kq][padded pixel] 4x f16 channels
    __shared__ unsigned j2buf[256][9];      // 9-word rows: conflict-free
    __shared__ int s_af1, s_af2;
    const int t = threadIdx.x;

    {
        const uint4* a = (const uint4*)(ws + OFF_W1A);
        uint4* da = (uint4*)s_w1a;
        for (int i = t; i < 384; i += 256) da[i] = a[i];
        const uint4* b = (const uint4*)(ws + OFF_W2A);
        uint4* db = (uint4*)s_w2a;
        for (int i = t; i < 384; i += 256) db[i] = b[i];
        const uint4* c = (const uint4*)(ws + OFF_WDWH);
        uint4* dc = (uint4*)s_wdwh;
        for (int i = t; i < 216; i += 256) dc[i] = c[i];
        const float* f1 = (const float*)(ws + OFF_FQ1);
        const float* f2 = (const float*)(ws + OFF_FQ2);
        for (int i = t; i < 192; i += 256) {
            s_fqA1[i] = f1[i]; s_fqB1[i] = f1[192+i];
            s_fqA2[i] = f2[i]; s_fqB2[i] = f2[192+i];
        }
        const float* b3p = (const float*)(ws + OFF_BN3);
        if (t < 96) s_bn3[t] = b3p[t];
        if (t == 0) {
            s_af1 = (int)((const unsigned*)(ws + OFF_FQ1))[576];
            s_af2 = (int)((const unsigned*)(ws + OFF_FQ2))[576];
        }
    }

    const unsigned* scal = (const unsigned*)(ws + OFF_SCAL);
    const float* wsc = (const float*)(ws + OFF_WSC);
    const float* gbn1 = (const float*)(ws + OFF_BN1);   // fallback only
    const float* gbn2 = (const float*)(ws + OFF_BN2);   // fallback only
    const unsigned char* xq = ws + OFF_XQ;

    const float sx  = __uint_as_float(scal[0]) + 1e-8f;
    const float s1v = __uint_as_float(scal[1]) + 1e-8f;
    const float s2v = __uint_as_float(scal[2]) + 1e-8f;
    const float C1  = (float)(((double)sx  / 7.0)  * ((double)wsc[0] / 7.0));
    const float C2  = (float)(((double)s1v / 15.0) * ((double)wsc[1] / 7.0));
    const float C3  = (float)(((double)s2v / 15.0) * ((double)wsc[2] / 7.0));

    const int tile = blockIdx.x, n = blockIdx.y;
    const int y0 = (tile >> 3) * 14, x0 = (tile & 7) * 14;
    const int lane = t & 63, wid = t >> 6;
    const int ty = t >> 4, tx = t & 15;
    const bool act = (ty < 14) && (tx < 14);
    const int px = lane & 15, kq = lane >> 4;

    // conv1 B-fragments: group g = 4*wid+i, pixel = g*16 + px, 8 bytes at kq*8
    ull  xb[4];
    bool okb[4];
#pragma unroll
    for (int i = 0; i < 4; ++i) {
        int g = 4*wid + i;
        int bhy = y0 - 1 + g, bwx = x0 - 1 + px;
        bool ok = (bhy >= 0) && (bhy < WID) && (bwx >= 0) && (bwx < WID);
        okb[i] = ok;
        ull v = 0;
        if (ok) v = *(const ull*)(xq + (((size_t)n * HW + bhy * WID + bwx) * 32 + kq * 8));
        xb[i] = v;
    }
    __syncthreads();   // staging complete

    v4i acc2[2][4];
#pragma unroll
    for (int o = 0; o < 2; ++o)
#pragma unroll
        for (int i = 0; i < 4; ++i) { acc2[o][i][0]=0; acc2[o][i][1]=0; acc2[o][i][2]=0; acc2[o][i][3]=0; }

    for (int ph = 0; ph < 12; ++ph) {
        // ---- conv1 MFMA: 16 oc x 64 pixels per wave; j1 -> f16 quads in LDS ----
        ull a1 = s_w1a[ph*64 + lane];
        const int oc0 = ph*16 + kq*4;
        float4 A14 = *(const float4*)&s_fqA1[oc0];
        float4 B14 = *(const float4*)&s_fqB1[oc0];
#pragma unroll
        for (int i = 0; i < 4; ++i) {
            v4i z = {0,0,0,0};
            v4i d = mfma_i8(a1, xb[i], z);
            float4 j1v;
            if (s_af1) {
                j1v.x = okb[i] ? qfast15((float)d[0], A14.x, B14.x) : 0.f;
                j1v.y = okb[i] ? qfast15((float)d[1], A14.y, B14.y) : 0.f;
                j1v.z = okb[i] ? qfast15((float)d[2], A14.z, B14.z) : 0.f;
                j1v.w = okb[i] ? qfast15((float)d[3], A14.w, B14.w) : 0.f;
            } else {
                float jj[4];
#pragma unroll
                for (int r = 0; r < 4; ++r) {
                    int oc = oc0 + r;
                    float h1 = bnq((float)d[r], C1, gbn1[192+oc], gbn1[oc], gbn1[384+oc]);
                    jj[r] = okb[i] ? qexact15(h1, s1v) : 0.f;
                }
                j1v.x = jj[0]; j1v.y = jj[1]; j1v.z = jj[2]; j1v.w = jj[3];
            }
            jlh[kq][PADP((4*wid + i)*16 + px)] =
                make_uint2(h2u(pkrtz(j1v.x, j1v.y)), h2u(pkrtz(j1v.z, j1v.w)));
        }
        __syncthreads();   // A: jlh ready

        // ---- dw on packed f16 (exact for these integer ranges) + j2 pack ----
        unsigned pw[4] = {0u, 0u, 0u, 0u};
        if (act) {
#pragma unroll
            for (int q = 0; q < 4; ++q) {
                h2 s01 = u2h(0u), s23 = u2h(0u);
                const int qg = ph*4 + q;
#pragma unroll
                for (int dy = 0; dy < 3; ++dy)
#pragma unroll
                    for (int dx = 0; dx < 3; ++dx) {
                        uint2 jv = jlh[q][PADP((ty+dy)*16 + (tx+dx))];
                        uint2 wv = s_wdwh[qg*9 + dy*3 + dx];
                        s01 += u2h(jv.x) * u2h(wv.x);
                        s23 += u2h(jv.y) * u2h(wv.y);
                    }
                float f0 = (float)s01[0], f1 = (float)s01[1];
                float f2 = (float)s23[0], f3 = (float)s23[1];
                const int oc2 = ph*16 + q*4;
                float j2a, j2b, j2c, j2d;
                if (s_af2) {
                    float4 A24 = *(const float4*)&s_fqA2[oc2];
                    float4 B24 = *(const float4*)&s_fqB2[oc2];
                    j2a = qfast15(f0, A24.x, B24.x);
                    j2b = qfast15(f1, A24.y, B24.y);
                    j2c = qfast15(f2, A24.z, B24.z);
                    j2d = qfast15(f3, A24.w, B24.w);
                } else {
                    j2a = qexact15(bnq(f0, C2, gbn2[192+oc2],   gbn2[oc2],   gbn2[384+oc2]),   s2v);
                    j2b = qexact15(bnq(f1, C2, gbn2[192+oc2+1], gbn2[oc2+1], gbn2[384+oc2+1]), s2v);
                    j2c = qexact15(bnq(f2, C2, gbn2[192+oc2+2], gbn2[oc2+2], gbn2[384+oc2+2]), s2v);
                    j2d = qexact15(bnq(f3, C2, gbn2[192+oc2+3], gbn2[oc2+3], gbn2[384+oc2+3]), s2v);
                }
                pw[q] = ((unsigned)(int)j2a) | ((unsigned)(int)j2b << 8) |
                        ((unsigned)(int)j2c << 16) | ((unsigned)(int)j2d << 24);
            }
        }
#pragma unroll
        for (int q = 0; q < 4; ++q) j2buf[t][(ph & 1) * 4 + q] = pw[q];
        __syncthreads();   // B: dw reads done, j2buf slot written

        // ---- conv2 MFMA for the completed 32-channel chunk (odd phases) ----
        // next phase's barrier A orders these reads before the next j2buf writes
        if (ph & 1) {
            const int chunk = ph >> 1;
#pragma unroll
            for (int oct = 0; oct < 2; ++oct) {
                ull a2 = s_w2a[(oct*6 + chunk)*64 + lane];
#pragma unroll
                for (int i = 0; i < 4; ++i) {
                    int row = (4*wid + i)*16 + px;
                    unsigned w0 = j2buf[row][kq*2], w1 = j2buf[row][kq*2 + 1];
                    ull b2 = (ull)w0 | ((ull)w1 << 32);
                    acc2[oct][i] = mfma_i8(a2, b2, acc2[oct][i]);
                }
            }
        }
    }

    // ---- bn3 + store h3 + max|h3| ----
    float mx = 0.f;
#pragma unroll
    for (int oct = 0; oct < 2; ++oct)
#pragma unroll
        for (int i = 0; i < 4; ++i) {
            int g = 4*wid + i;
            if (g < 14 && px < 14) {
                int gy = y0 + g, gx = x0 + px;
#pragma unroll
                for (int r = 0; r < 4; ++r) {
                    int oc = oct*16 + kq*4 + r;
                    float y = __fmul_rn((float)acc2[oct][i][r], C3);
                    float h = __fadd_rn(__fmul_rn(__fsub_rn(y, s_bn3[32+oc]), s_bn3[oc]), s_bn3[64+oc]);
                    h3[((size_t)n * COUT + oc) * HW + gy * WID + gx] = h;
                    mx = fmaxf(mx, fabsf(h));
                }
            }
        }
    __syncthreads();                       // all j2buf reads done before overlay
    float* red = (float*)&j2buf[0][0];     // reuse j2buf space for reduction
    float r = bmax256(mx, red);
    if (t == 0) atomicMax((unsigned*)(ws + OFF_SCAL) + 3, __float_as_uint(r));
}

// in-place on d_out: out = x + actq_signed(h3)
__global__ __launch_bounds__(256) void kout(const float4* __restrict__ x4,
                                            float4* __restrict__ io4,
                                            const unsigned char* __restrict__ ws)
{
    const unsigned* scal = (const unsigned*)(ws + OFF_SCAL);
    const float s3v = __uint_as_float(scal[3]) + 1e-8f;

    for (size_t i = (size_t)blockIdx.x*256 + threadIdx.x; i < NX/4; i += (size_t)gridDim.x*256) {
        float4 h = io4[i], xv = x4[i], o;
        float* hp = &h.x; float* xp = &xv.x; float* op = &o.x;
#pragma unroll
        for (int k = 0; k < 4; ++k) {
            float tq = fminf(fmaxf(hp[k] / s3v, -1.f), 1.f);
            float kq = rintf(__fmul_rn(tq, 7.f));
            float q  = __fmul_rn(kq / 7.f, s3v);
            op[k] = __fadd_rn(xp[k], q);
        }
        io4[i] = o;
    }
}

extern "C" void kernel_launch(void* const* d_in, const int* in_sizes, int n_in,
                              void* d_out, int out_size, void* d_ws, size_t ws_size,
                              hipStream_t stream)
{
    const float* x   = (const float*)d_in[0];
    const float* w1  = (const float*)d_in[1];
    const float* g1  = (const float*)d_in[2];
    const float* b1  = (const float*)d_in[3];
    const float* m1  = (const float*)d_in[4];
    const float* v1  = (const float*)d_in[5];
    const float* wdw = (const float*)d_in[6];
    const float* g2  = (const float*)d_in[7];
    const float* b2  = (const float*)d_in[8];
    const float* m2  = (const float*)d_in[9];
    const float* v2  = (const float*)d_in[10];
    const float* w2  = (const float*)d_in[11];
    const float* g3  = (const float*)d_in[12];
    const float* b3  = (const float*)d_in[13];
    const float* m3  = (const float*)d_in[14];
    const float* v3  = (const float*)d_in[15];
    unsigned char* ws = (unsigned char*)d_ws;

    hipLaunchKernelGGL(kprepx, dim3(2048), dim3(256), 0, stream, (const float4*)x,
                       w1, wdw, w2, g1, b1, m1, v1, g2, b2, m2, v2, g3, b3, m3, v3, ws);
    hipLaunchKernelGGL(kmax1q, dim3(NPIX/256), dim3(256), 0, stream, x, ws);
    hipLaunchKernelGGL(kcoef, dim3(CMID), dim3(64), 0, stream, ws, 1);
    hipLaunchKernelGGL(kmax2, dim3(64, NB), dim3(256), 0, stream, ws);
    hipLaunchKernelGGL(kcoef, dim3(CMID), dim3(64), 0, stream, ws, 2);
    hipLaunchKernelGGL(kconv2, dim3(64, NB), dim3(256), 0, stream, ws, (float*)d_out);
    hipLaunchKernelGGL(kout, dim3(2048), dim3(256), 0, stream,
                       (const float4*)x, (float4*)d_out, ws);
}